// Round 14
// baseline (138.245 us; speedup 1.0000x reference)
//
#include <hip/hip_runtime.h>
#include <math.h>

#define DIM     512
#define NNODES  10000
#define NEDGES  200000
#define MPAD    10240   // 160 * 64 (padded so XCD packing is exact)
#define NMB     160     // m-groups of 64
#define GEMM_GRID (NMB * 4)       // 640 pure-GEMM blocks
#define BKT     313               // r>>5 buckets (32 rows = 33KB fp16 LDS)
#define SPLIT   4                 // score blocks per bucket
#define ROWP    520               // padded LDS row stride (halves): breaks banks

using floatx4 = __attribute__((ext_vector_type(4))) float;
using half8   = __attribute__((ext_vector_type(8))) _Float16;
using half2v  = __attribute__((ext_vector_type(2))) _Float16;
typedef unsigned long long ull;

template <int N> struct IC { static constexpr int v = N; };

__device__ inline float dot2acc(half2v a, half2v b, float c) {
#if __has_builtin(__builtin_amdgcn_fdot2)
    return __builtin_amdgcn_fdot2(a, b, c, false);
#else
    return fmaf((float)a[0], (float)b[0], fmaf((float)a[1], (float)b[1], c));
#endif
}

// ---------------------------------------------------------------------------
// prep: (a) Z fp32 -> Zh16 fp16 (pad rows zeroed)  (b) W -> Wh16t transpose
//       (c) block 0 zeroes counts[313]. (R9-verbatim otherwise.)
// Strategy note: sort returns as THREE SEPARATE tiny dispatches (no flags,
// no intra-kernel waits -- R12's inversion and R11's race are impossible at
// dispatch boundaries). Its sole purpose now: let the scorer stage the
// r-side rows in LDS, deleting 200MB of the 400MB logical gather (R9/R13
// counters: scorer is L2-miss-path-bound at ~3.4 TB/s).
// ---------------------------------------------------------------------------
#define PREP_ZBLK 2560            // MPAD*512/(256*8)
#define PREP_GRID (PREP_ZBLK + 64)
__global__ __launch_bounds__(256) void prep(const float* __restrict__ Z,
                                            const float* __restrict__ W,
                                            _Float16* __restrict__ Zh16,
                                            _Float16* __restrict__ Wh16t,
                                            int* __restrict__ counts) {
    const int b = blockIdx.x;
    const int t = threadIdx.x;

    if (b == 0) {
        if (t < BKT) counts[t] = 0;
        if (t + 256 < BKT) counts[t + 256] = 0;
    }

    if (b < PREP_ZBLK) {
        const int idx8 = (b * 256 + t) * 8;
        const int m = idx8 >> 9;
        float x[8];
        if (m < NNODES) {
            float4 v0 = *(const float4*)(Z + idx8);
            float4 v1 = *(const float4*)(Z + idx8 + 4);
            x[0]=v0.x; x[1]=v0.y; x[2]=v0.z; x[3]=v0.w;
            x[4]=v1.x; x[5]=v1.y; x[6]=v1.z; x[7]=v1.w;
        } else {
            #pragma unroll
            for (int j = 0; j < 8; ++j) x[j] = 0.f;
        }
        half8 h;
        #pragma unroll
        for (int j = 0; j < 8; ++j) h[j] = (_Float16)x[j];
        *(half8*)(Zh16 + idx8) = h;
    } else {
        __shared__ float tile[64][65];
        const int wb = b - PREP_ZBLK;      // 0..63
        const int kb = (wb >> 3) * 64;
        const int nb = (wb & 7) * 64;
        const int kk = t >> 2;
        const int ch = t & 3;

        const float* src = W + (size_t)(kb + kk) * DIM + nb + ch * 16;
        #pragma unroll
        for (int q = 0; q < 4; ++q) {
            float4 v = *(const float4*)(src + q * 4);
            tile[kk][ch * 16 + q * 4 + 0] = v.x;
            tile[kk][ch * 16 + q * 4 + 1] = v.y;
            tile[kk][ch * 16 + q * 4 + 2] = v.z;
            tile[kk][ch * 16 + q * 4 + 3] = v.w;
        }
        __syncthreads();

        const int nn = kk;
        half8 h0, h1;
        #pragma unroll
        for (int i = 0; i < 8; ++i) h0[i] = (_Float16)tile[ch * 16 + i][nn];
        #pragma unroll
        for (int i = 0; i < 8; ++i) h1[i] = (_Float16)tile[ch * 16 + 8 + i][nn];
        _Float16* d = Wh16t + (size_t)(nb + nn) * DIM + kb + ch * 16;
        *(half8*)(d)     = h0;
        *(half8*)(d + 8) = h1;
    }
}

// ---------------------------------------------------------------------------
// Sort dispatch 1/3: LDS-aggregated histogram by r>>5.
// ---------------------------------------------------------------------------
__global__ __launch_bounds__(256) void hist_k(const int* __restrict__ eidx,
                                              int* __restrict__ counts) {
    __shared__ int s_cnt[BKT];
    const int t = threadIdx.x;
    for (int i = t; i < BKT; i += 256) s_cnt[i] = 0;
    __syncthreads();
    for (int e = blockIdx.x * 256 + t; e < NEDGES; e += 64 * 256)
        atomicAdd(&s_cnt[eidx[e] >> 5], 1);
    __syncthreads();
    for (int i = t; i < BKT; i += 256)
        if (s_cnt[i]) atomicAdd(&counts[i], s_cnt[i]);
}

// Sort dispatch 2/3: single-block exclusive scan (313 <= 512 threads).
__global__ __launch_bounds__(512) void scan_k(const int* __restrict__ counts,
                                              int* __restrict__ bstart,
                                              int* __restrict__ cursor) {
    __shared__ int s[512];
    const int t = threadIdx.x;
    int v = (t < BKT) ? counts[t] : 0;
    s[t] = v;
    __syncthreads();
    #pragma unroll
    for (int off = 1; off < 512; off <<= 1) {
        int u = (t >= off) ? s[t - off] : 0;
        __syncthreads();
        s[t] += u;
        __syncthreads();
    }
    if (t < BKT) {
        const int ex = s[t] - v;
        bstart[t] = ex;
        cursor[t] = ex;
    }
    if (t == 0) bstart[BKT] = NEDGES;
}

// Sort dispatch 3/3: LDS range-reservation scatter into r-sorted slots.
#define SCAT_BLKS 196   // 196*1024 >= 200000
__global__ __launch_bounds__(256) void scatter_k(const int* __restrict__ eidx,
                                                 int* __restrict__ cursor,
                                                 ull* __restrict__ slots) {
    __shared__ int s_cnt[BKT], s_base[BKT], s_off[BKT];
    const int t = threadIdx.x;
    for (int i = t; i < BKT; i += 256) { s_cnt[i] = 0; s_off[i] = 0; }
    __syncthreads();
    const int e0 = blockIdx.x * 1024;
    int myb[4];
    #pragma unroll
    for (int q = 0; q < 4; ++q) {
        int e = e0 + q * 256 + t;
        if (e < NEDGES) { myb[q] = eidx[e] >> 5; atomicAdd(&s_cnt[myb[q]], 1); }
        else myb[q] = -1;
    }
    __syncthreads();
    for (int i = t; i < BKT; i += 256)
        if (s_cnt[i]) s_base[i] = atomicAdd(&cursor[i], s_cnt[i]);
    __syncthreads();
    #pragma unroll
    for (int q = 0; q < 4; ++q)
        if (myb[q] >= 0) {
            int e = e0 + q * 256 + t;
            int r = eidx[e];
            int c = eidx[NEDGES + e];
            int pos = s_base[myb[q]] + atomicAdd(&s_off[myb[q]], 1);
            slots[pos] = ((ull)(unsigned)r << 32) |
                         (ull)(((unsigned)c << 18) | (unsigned)e);
        }
}

// ---------------------------------------------------------------------------
// Pure GEMM: 64x128 tiles, counted-vmcnt 2-deep pipeline (R7) + XCD packing
// (R6). R9-verbatim (~25us standalone).
// ---------------------------------------------------------------------------
__global__ __launch_bounds__(256, 3) void gemm_f16(
        const _Float16* __restrict__ Zh16,
        const _Float16* __restrict__ Wh16t,
        _Float16* __restrict__ ZWh)
{
    __shared__ _Float16 Abuf[2][2 * 64 * 32];    // 16 KB
    __shared__ _Float16 Bbuf[2][2 * 128 * 32];   // 32 KB

    const int t   = threadIdx.x;
    const int bid = blockIdx.x;

    const int cxd = bid & 7;              // XCD class (bid%8 -> XCD)
    const int rr  = bid >> 3;             // 0..79
    const int mg  = (rr >> 2) * 8 + cxd;  // 0..159, same-m => same XCD
    const int m0  = mg * 64;
    const int n0  = (rr & 3) * 128;

    const int l  = t & 63;
    const int w  = t >> 6;
    const int wn = w * 32;
    const int lm = l & 15;
    const int lq = l >> 4;
    const unsigned wbase = (unsigned)(t & 192);

    floatx4 acc[4][2] = {};

    auto stage = [&](int buf, int k0) {    // 6 global_load_lds / thread
        #pragma unroll
        for (int p = 0; p < 2; ++p) {
            const int s   = p * 256 + t;
            const int kk  = s >> 8;
            const int row = (s >> 2) & 63;
            const int ch  = s & 3;
            const _Float16* src = Zh16 + (size_t)(m0 + row) * DIM + k0 + kk * 32 + ch * 8;
            __builtin_amdgcn_global_load_lds(
                (const __attribute__((address_space(1))) void*)src,
                (__attribute__((address_space(3))) void*)&Abuf[buf][(p * 256 + wbase) * 8],
                16, 0, 0);
        }
        #pragma unroll
        for (int p = 0; p < 4; ++p) {
            const int s   = p * 256 + t;
            const int kk  = s >> 9;
            const int row = (s >> 2) & 127;
            const int ch  = s & 3;
            const _Float16* src = Wh16t + (size_t)(n0 + row) * DIM + k0 + kk * 32 + ch * 8;
            __builtin_amdgcn_global_load_lds(
                (const __attribute__((address_space(1))) void*)src,
                (__attribute__((address_space(3))) void*)&Bbuf[buf][(p * 256 + wbase) * 8],
                16, 0, 0);
        }
    };

    stage(0, 0);
    stage(1, 64);          // 12 loads in flight

    auto step = [&](auto Sc) {
        constexpr int S   = decltype(Sc)::v;
        constexpr int buf = S & 1;
        if constexpr (S < 7) asm volatile("s_waitcnt vmcnt(6)" ::: "memory");
        else                 asm volatile("s_waitcnt vmcnt(0)" ::: "memory");
        __builtin_amdgcn_sched_barrier(0);
        __builtin_amdgcn_s_barrier();          // all waves' stage(S) landed
        __builtin_amdgcn_sched_barrier(0);

        half8 aF[2][4], bF[2][2];
        #pragma unroll
        for (int kk = 0; kk < 2; ++kk) {
            #pragma unroll
            for (int i = 0; i < 4; ++i)
                aF[kk][i] = *(const half8*)&Abuf[buf][kk * 2048 + (16 * i + lm) * 32 + lq * 8];
            #pragma unroll
            for (int j = 0; j < 2; ++j)
                bF[kk][j] = *(const half8*)&Bbuf[buf][kk * 4096 + (wn + 16 * j + lm) * 32 + lq * 8];
        }
        asm volatile("s_waitcnt lgkmcnt(0)" ::: "memory");
        __builtin_amdgcn_sched_barrier(0);
        __builtin_amdgcn_s_barrier();          // WAR: all waves read buf
        __builtin_amdgcn_sched_barrier(0);

        if constexpr (S < 6) stage(buf, (S + 2) * 64);   // refill freed buf

        #pragma unroll
        for (int kk = 0; kk < 2; ++kk)
            #pragma unroll
            for (int i = 0; i < 4; ++i)
                #pragma unroll
                for (int j = 0; j < 2; ++j)
                    acc[i][j] = __builtin_amdgcn_mfma_f32_16x16x32_f16(
                        aF[kk][i], bF[kk][j], acc[i][j], 0, 0, 0);
    };

    step(IC<0>{}); step(IC<1>{}); step(IC<2>{}); step(IC<3>{});
    step(IC<4>{}); step(IC<5>{}); step(IC<6>{}); step(IC<7>{});

    #pragma unroll
    for (int i = 0; i < 4; ++i)
        #pragma unroll
        for (int j = 0; j < 2; ++j)
            #pragma unroll
            for (int r = 0; r < 4; ++r) {
                const int gm = m0 + 16 * i + lq * 4 + r;
                const int gn = n0 + wn + 16 * j + lm;
                if (gm < NNODES)
                    ZWh[(size_t)gm * DIM + gn] = (_Float16)acc[i][j][r];
            }
}

// ---------------------------------------------------------------------------
// Edge scoring, r-bucketed: block = (bucket b, quarter). Stages the bucket's
// 32 ZW rows into LDS once (33KB, padded stride vs bank conflicts), then
// streams its edge quarter: r-row from LDS (global r-gather DELETED),
// c-row 64B/lane from global, same fp32 dot + 16-lane reduce as R9.
// ---------------------------------------------------------------------------
__global__ __launch_bounds__(256) void edge_score_s(const _Float16* __restrict__ ZWh,
                                                    const _Float16* __restrict__ Zh,
                                                    const ull* __restrict__ slots,
                                                    const int* __restrict__ bstart,
                                                    float* __restrict__ out) {
    __shared__ _Float16 rows[32 * ROWP];   // 33,280 B

    const int t   = threadIdx.x;
    const int b   = blockIdx.x / SPLIT;    // bucket 0..312
    const int qtr = blockIdx.x % SPLIT;
    const int r0  = b * 32;

    // stage 32 rows (guard tail bucket): 2048 16B-chunks, 8 per thread
    #pragma unroll
    for (int k = 0; k < 8; ++k) {
        const int i   = t + k * 256;
        const int row = i >> 6;            // 64 chunks per row
        const int off = i & 63;
        if (r0 + row < NNODES) {
            half8 v = *(const half8*)(ZWh + (size_t)(r0 + row) * DIM + off * 8);
            *(half8*)(rows + row * ROWP + off * 8) = v;
        }
    }
    __syncthreads();

    const int s0  = bstart[b];
    const int s1  = bstart[b + 1];
    const int len = s1 - s0;
    const int q0  = s0 + (len * qtr) / SPLIT;
    const int q1  = s0 + (len * (qtr + 1)) / SPLIT;

    const int l  = t & 63;
    const int w  = t >> 6;
    const int gq = l >> 4;
    const int sl = l & 15;

    for (int base = q0; base < q1; base += 16) {
        const int idx = base + w * 4 + gq;
        float sa = 0.f, sb = 0.f;
        int e = -1;
        if (idx < q1) {
            const ull v = slots[idx];
            e = (int)(v & 0x3FFFFu);
            const int c  = (int)((v >> 18) & 0x3FFFu);
            const int rl = (int)(v >> 32) - r0;

            const _Float16* rp = rows + rl * ROWP + sl * 32;
            const _Float16* cp = Zh + (size_t)c * DIM + sl * 32;

            half8 ra0 = *(const half8*)(rp);
            half8 ra1 = *(const half8*)(rp + 8);
            half8 ra2 = *(const half8*)(rp + 16);
            half8 ra3 = *(const half8*)(rp + 24);
            half8 c0  = *(const half8*)(cp);
            half8 c1  = *(const half8*)(cp + 8);
            half8 c2  = *(const half8*)(cp + 16);
            half8 c3  = *(const half8*)(cp + 24);

            #pragma unroll
            for (int d = 0; d < 4; ++d) {
                sa = dot2acc((half2v){ra0[2*d], ra0[2*d+1]}, (half2v){c0[2*d], c0[2*d+1]}, sa);
                sb = dot2acc((half2v){ra1[2*d], ra1[2*d+1]}, (half2v){c1[2*d], c1[2*d+1]}, sb);
                sa = dot2acc((half2v){ra2[2*d], ra2[2*d+1]}, (half2v){c2[2*d], c2[2*d+1]}, sa);
                sb = dot2acc((half2v){ra3[2*d], ra3[2*d+1]}, (half2v){c3[2*d], c3[2*d+1]}, sb);
            }
        }
        float s = sa + sb;
        s += __shfl_xor(s, 1, 64);
        s += __shfl_xor(s, 2, 64);
        s += __shfl_xor(s, 4, 64);
        s += __shfl_xor(s, 8, 64);
        if (sl == 0 && e >= 0)
            out[e] = 1.0f / (1.0f + expf(-s));
    }
}

// ---------------------------------------------------------------------------
// fp32 fallback path (ws too small)
// ---------------------------------------------------------------------------
#define GTM 128
#define GTN 64
#define GTK 16
#define LDA 132
#define LDB 68

__global__ __launch_bounds__(256) void gemm_zw(const float* __restrict__ A,
                                               const float* __restrict__ B,
                                               float* __restrict__ C) {
    __shared__ float As[GTK * LDA];
    __shared__ float Bs[GTK * LDB];

    const int t  = threadIdx.x;
    const int m0 = blockIdx.x * GTM;
    const int n0 = blockIdx.y * GTN;
    const int tx = t & 15;
    const int ty = t >> 4;

    float acc[8][4] = {};

    for (int k0 = 0; k0 < DIM; k0 += GTK) {
        #pragma unroll
        for (int p = 0; p < 2; ++p) {
            int f  = t + p * 256;
            int mm = f >> 2;
            int kq = f & 3;
            int m  = m0 + mm;
            float4 v = make_float4(0.f, 0.f, 0.f, 0.f);
            if (m < NNODES)
                v = *(const float4*)(A + (size_t)m * DIM + k0 + kq * 4);
            As[(kq * 4 + 0) * LDA + mm] = v.x;
            As[(kq * 4 + 1) * LDA + mm] = v.y;
            As[(kq * 4 + 2) * LDA + mm] = v.z;
            As[(kq * 4 + 3) * LDA + mm] = v.w;
        }
        {
            int kb = t >> 4, n4 = t & 15;
            *(float4*)&Bs[kb * LDB + n4 * 4] =
                *(const float4*)(B + (size_t)(k0 + kb) * DIM + n0 + n4 * 4);
        }
        __syncthreads();

        #pragma unroll
        for (int kk = 0; kk < GTK; ++kk) {
            float4 a0 = *(const float4*)&As[kk * LDA + ty * 8];
            float4 a1 = *(const float4*)&As[kk * LDA + ty * 8 + 4];
            float4 b  = *(const float4*)&Bs[kk * LDB + tx * 4];
            float av[8] = {a0.x, a0.y, a0.z, a0.w, a1.x, a1.y, a1.z, a1.w};
            float bv[4] = {b.x, b.y, b.z, b.w};
            #pragma unroll
            for (int i = 0; i < 8; ++i)
                #pragma unroll
                for (int j = 0; j < 4; ++j)
                    acc[i][j] = fmaf(av[i], bv[j], acc[i][j]);
        }
        __syncthreads();
    }

    #pragma unroll
    for (int i = 0; i < 8; ++i) {
        int m = m0 + ty * 8 + i;
        if (m < NNODES)
            *(float4*)(C + (size_t)m * DIM + n0 + tx * 4) =
                make_float4(acc[i][0], acc[i][1], acc[i][2], acc[i][3]);
    }
}

__global__ __launch_bounds__(256) void edge_score(const float* __restrict__ ZW,
                                                  const float* __restrict__ Z,
                                                  const int* __restrict__ eidx,
                                                  float* __restrict__ out) {
    const int e    = blockIdx.x * 4 + (threadIdx.x >> 6);
    const int lane = threadIdx.x & 63;

    const int r = eidx[e];
    const int c = eidx[NEDGES + e];

    const float4* pr = (const float4*)(ZW + (size_t)r * DIM);
    const float4* pc = (const float4*)(Z  + (size_t)c * DIM);

    float4 a0 = pr[lane * 2 + 0];
    float4 a1 = pr[lane * 2 + 1];
    float4 b0 = pc[lane * 2 + 0];
    float4 b1 = pc[lane * 2 + 1];

    float s = a0.x * b0.x;
    s = fmaf(a0.y, b0.y, s);
    s = fmaf(a0.z, b0.z, s);
    s = fmaf(a0.w, b0.w, s);
    s = fmaf(a1.x, b1.x, s);
    s = fmaf(a1.y, b1.y, s);
    s = fmaf(a1.z, b1.z, s);
    s = fmaf(a1.w, b1.w, s);

    #pragma unroll
    for (int off = 32; off > 0; off >>= 1)
        s += __shfl_xor(s, off, 64);

    if (lane == 0)
        out[e] = 1.0f / (1.0f + expf(-s));
}

// ---------------------------------------------------------------------------
extern "C" void kernel_launch(void* const* d_in, const int* in_sizes, int n_in,
                              void* d_out, int out_size, void* d_ws, size_t ws_size,
                              hipStream_t stream) {
    const float* Z  = (const float*)d_in[0];
    const float* W  = (const float*)d_in[1];
    const int*   EI = (const int*)d_in[2];
    float* out = (float*)d_out;

    char* p = (char*)d_ws;
    _Float16* ZWh   = (_Float16*)p;  p += (size_t)MPAD * DIM * 2;
    _Float16* Zh16  = (_Float16*)p;  p += (size_t)MPAD * DIM * 2;
    _Float16* Wh16t = (_Float16*)p;  p += (size_t)DIM * DIM * 2;
    int* counts  = (int*)p;          p += (size_t)BKT * 4;
    int* bstart  = (int*)p;          p += (size_t)(BKT + 1) * 4;
    int* cursor  = (int*)p;          p += (size_t)BKT * 4;
    ull* slots   = (ull*)p;          p += (size_t)NEDGES * 8;
    const size_t need_full = (size_t)(p - (char*)d_ws);

    if (ws_size >= need_full) {
        prep<<<PREP_GRID, 256, 0, stream>>>(Z, W, Zh16, Wh16t, counts);
        hist_k<<<64, 256, 0, stream>>>(EI, counts);
        scan_k<<<1, 512, 0, stream>>>(counts, bstart, cursor);
        scatter_k<<<SCAT_BLKS, 256, 0, stream>>>(EI, cursor, slots);
        gemm_f16<<<GEMM_GRID, 256, 0, stream>>>(Zh16, Wh16t, ZWh);
        edge_score_s<<<BKT * SPLIT, 256, 0, stream>>>(ZWh, Zh16, slots, bstart, out);
    } else {
        float* ZW = (float*)d_ws;
        dim3 g1((NNODES + GTM - 1) / GTM, DIM / GTN);
        gemm_zw<<<g1, 256, 0, stream>>>(Z, W, ZW);
        edge_score<<<NEDGES / 4, 256, 0, stream>>>(ZW, Z, EI, out);
    }
}

// Round 15
// 128.961 us; speedup vs baseline: 1.0720x; 1.0720x over previous
//
#include <hip/hip_runtime.h>
#include <math.h>

#define DIM     512
#define NNODES  10000
#define NEDGES  200000
#define MPAD    10240   // 160 * 64 (padded so XCD packing is exact)
#define NMB     160     // m-groups of 64
#define GEMM_GRID (NMB * 4)       // 640 pure-GEMM blocks

using floatx4 = __attribute__((ext_vector_type(4))) float;
using half8   = __attribute__((ext_vector_type(8))) _Float16;
using half2v  = __attribute__((ext_vector_type(2))) _Float16;

template <int N> struct IC { static constexpr int v = N; };

__device__ inline float dot2acc(half2v a, half2v b, float c) {
#if __has_builtin(__builtin_amdgcn_fdot2)
    return __builtin_amdgcn_fdot2(a, b, c, false);
#else
    return fmaf((float)a[0], (float)b[0], fmaf((float)a[1], (float)b[1], c));
#endif
}

// ---------------------------------------------------------------------------
// R15 = R9 verbatim (best harness-verified: 128.7us).
// Session ledger: sort/locality restructures of the scorer failed 3x
// (R10 c-window+XCD-pin: +3.5; R13 MLP-double: +9.4; R14 r-LDS+3-dispatch
// sort: +9.5) -- the random row-gather saturates the L2-miss path at
// ~3.4 TB/s regardless of which half is removed, and every sort costs more
// (~10us) than it recovers. GEMM variants bracket 24-68us with this config
// at the bottom. Fill (~45us, 256MiB harness re-poison) is fixed overhead.
// ---------------------------------------------------------------------------
#define PREP_ZBLK 2560            // MPAD*512/(256*8)
#define PREP_GRID (PREP_ZBLK + 64)
__global__ __launch_bounds__(256) void prep(const float* __restrict__ Z,
                                            const float* __restrict__ W,
                                            _Float16* __restrict__ Zh16,
                                            _Float16* __restrict__ Wh16t) {
    const int b = blockIdx.x;
    const int t = threadIdx.x;

    if (b < PREP_ZBLK) {
        const int idx8 = (b * 256 + t) * 8;
        const int m = idx8 >> 9;
        float x[8];
        if (m < NNODES) {
            float4 v0 = *(const float4*)(Z + idx8);
            float4 v1 = *(const float4*)(Z + idx8 + 4);
            x[0]=v0.x; x[1]=v0.y; x[2]=v0.z; x[3]=v0.w;
            x[4]=v1.x; x[5]=v1.y; x[6]=v1.z; x[7]=v1.w;
        } else {
            #pragma unroll
            for (int j = 0; j < 8; ++j) x[j] = 0.f;
        }
        half8 h;
        #pragma unroll
        for (int j = 0; j < 8; ++j) h[j] = (_Float16)x[j];
        *(half8*)(Zh16 + idx8) = h;
    } else {
        __shared__ float tile[64][65];
        const int wb = b - PREP_ZBLK;      // 0..63
        const int kb = (wb >> 3) * 64;
        const int nb = (wb & 7) * 64;
        const int kk = t >> 2;
        const int ch = t & 3;

        const float* src = W + (size_t)(kb + kk) * DIM + nb + ch * 16;
        #pragma unroll
        for (int q = 0; q < 4; ++q) {
            float4 v = *(const float4*)(src + q * 4);
            tile[kk][ch * 16 + q * 4 + 0] = v.x;
            tile[kk][ch * 16 + q * 4 + 1] = v.y;
            tile[kk][ch * 16 + q * 4 + 2] = v.z;
            tile[kk][ch * 16 + q * 4 + 3] = v.w;
        }
        __syncthreads();

        const int nn = kk;
        half8 h0, h1;
        #pragma unroll
        for (int i = 0; i < 8; ++i) h0[i] = (_Float16)tile[ch * 16 + i][nn];
        #pragma unroll
        for (int i = 0; i < 8; ++i) h1[i] = (_Float16)tile[ch * 16 + 8 + i][nn];
        _Float16* d = Wh16t + (size_t)(nb + nn) * DIM + kb + ch * 16;
        *(half8*)(d)     = h0;
        *(half8*)(d + 8) = h1;
    }
}

// ---------------------------------------------------------------------------
// Pure GEMM: 64x128 tiles, counted-vmcnt 2-deep pipeline (R7) + XCD packing
// (R6). Grid 640 @ 3 blocks/CU -> all blocks resident, single generation.
// ---------------------------------------------------------------------------
__global__ __launch_bounds__(256, 3) void gemm_f16(
        const _Float16* __restrict__ Zh16,
        const _Float16* __restrict__ Wh16t,
        _Float16* __restrict__ ZWh)
{
    __shared__ _Float16 Abuf[2][2 * 64 * 32];    // 16 KB
    __shared__ _Float16 Bbuf[2][2 * 128 * 32];   // 32 KB

    const int t   = threadIdx.x;
    const int bid = blockIdx.x;

    const int cxd = bid & 7;              // XCD class (bid%8 -> XCD)
    const int rr  = bid >> 3;             // 0..79
    const int mg  = (rr >> 2) * 8 + cxd;  // 0..159, same-m => same XCD
    const int m0  = mg * 64;
    const int n0  = (rr & 3) * 128;

    const int l  = t & 63;
    const int w  = t >> 6;
    const int wn = w * 32;
    const int lm = l & 15;
    const int lq = l >> 4;
    const unsigned wbase = (unsigned)(t & 192);

    floatx4 acc[4][2] = {};

    auto stage = [&](int buf, int k0) {    // 6 global_load_lds / thread
        #pragma unroll
        for (int p = 0; p < 2; ++p) {
            const int s   = p * 256 + t;
            const int kk  = s >> 8;
            const int row = (s >> 2) & 63;
            const int ch  = s & 3;
            const _Float16* src = Zh16 + (size_t)(m0 + row) * DIM + k0 + kk * 32 + ch * 8;
            __builtin_amdgcn_global_load_lds(
                (const __attribute__((address_space(1))) void*)src,
                (__attribute__((address_space(3))) void*)&Abuf[buf][(p * 256 + wbase) * 8],
                16, 0, 0);
        }
        #pragma unroll
        for (int p = 0; p < 4; ++p) {
            const int s   = p * 256 + t;
            const int kk  = s >> 9;
            const int row = (s >> 2) & 127;
            const int ch  = s & 3;
            const _Float16* src = Wh16t + (size_t)(n0 + row) * DIM + k0 + kk * 32 + ch * 8;
            __builtin_amdgcn_global_load_lds(
                (const __attribute__((address_space(1))) void*)src,
                (__attribute__((address_space(3))) void*)&Bbuf[buf][(p * 256 + wbase) * 8],
                16, 0, 0);
        }
    };

    stage(0, 0);
    stage(1, 64);          // 12 loads in flight

    auto step = [&](auto Sc) {
        constexpr int S   = decltype(Sc)::v;
        constexpr int buf = S & 1;
        // stage(S) complete; stage(S+1)'s 6 loads stay in flight
        if constexpr (S < 7) asm volatile("s_waitcnt vmcnt(6)" ::: "memory");
        else                 asm volatile("s_waitcnt vmcnt(0)" ::: "memory");
        __builtin_amdgcn_sched_barrier(0);
        __builtin_amdgcn_s_barrier();          // all waves' stage(S) landed
        __builtin_amdgcn_sched_barrier(0);

        half8 aF[2][4], bF[2][2];
        #pragma unroll
        for (int kk = 0; kk < 2; ++kk) {
            #pragma unroll
            for (int i = 0; i < 4; ++i)
                aF[kk][i] = *(const half8*)&Abuf[buf][kk * 2048 + (16 * i + lm) * 32 + lq * 8];
            #pragma unroll
            for (int j = 0; j < 2; ++j)
                bF[kk][j] = *(const half8*)&Bbuf[buf][kk * 4096 + (wn + 16 * j + lm) * 32 + lq * 8];
        }
        asm volatile("s_waitcnt lgkmcnt(0)" ::: "memory");
        __builtin_amdgcn_sched_barrier(0);
        __builtin_amdgcn_s_barrier();          // WAR: all waves read buf
        __builtin_amdgcn_sched_barrier(0);

        if constexpr (S < 6) stage(buf, (S + 2) * 64);   // refill freed buf

        #pragma unroll
        for (int kk = 0; kk < 2; ++kk)
            #pragma unroll
            for (int i = 0; i < 4; ++i)
                #pragma unroll
                for (int j = 0; j < 2; ++j)
                    acc[i][j] = __builtin_amdgcn_mfma_f32_16x16x32_f16(
                        aF[kk][i], bF[kk][j], acc[i][j], 0, 0, 0);
    };

    step(IC<0>{}); step(IC<1>{}); step(IC<2>{}); step(IC<3>{});
    step(IC<4>{}); step(IC<5>{}); step(IC<6>{}); step(IC<7>{});

    #pragma unroll
    for (int i = 0; i < 4; ++i)
        #pragma unroll
        for (int j = 0; j < 2; ++j)
            #pragma unroll
            for (int r = 0; r < 4; ++r) {
                const int gm = m0 + 16 * i + lq * 4 + r;
                const int gn = n0 + wn + 16 * j + lm;
                if (gm < NNODES)
                    ZWh[(size_t)gm * DIM + gn] = (_Float16)acc[i][j][r];
            }
}

// ---------------------------------------------------------------------------
// Edge scoring, UNSORTED: wave handles 4 edges straight from eidx; 16 lanes
// per edge; 8 independent b128 loads per lane. Tables are 21 MB total ->
// fully L3-resident; random order costs marginal locality while the output
// write stays contiguous.
// ---------------------------------------------------------------------------
__global__ __launch_bounds__(256) void edge_score_u(const _Float16* __restrict__ ZWh,
                                                    const _Float16* __restrict__ Zh,
                                                    const int* __restrict__ eidx,
                                                    float* __restrict__ out) {
    const int t    = threadIdx.x;
    const int lane = t & 63;
    const int gq   = lane >> 4;
    const int sl   = lane & 15;

    const int e = blockIdx.x * 16 + (t >> 6) * 4 + gq;
    const int r = eidx[e];
    const int c = eidx[NEDGES + e];

    const _Float16* rp = ZWh + (size_t)r * DIM + sl * 32;
    const _Float16* cp = Zh  + (size_t)c * DIM + sl * 32;

    half8 ra0 = *(const half8*)(rp);
    half8 ra1 = *(const half8*)(rp + 8);
    half8 ra2 = *(const half8*)(rp + 16);
    half8 ra3 = *(const half8*)(rp + 24);
    half8 c0  = *(const half8*)(cp);
    half8 c1  = *(const half8*)(cp + 8);
    half8 c2  = *(const half8*)(cp + 16);
    half8 c3  = *(const half8*)(cp + 24);

    float s = 0.f;
    #pragma unroll
    for (int d = 0; d < 4; ++d) {
        s = dot2acc((half2v){ra0[2*d], ra0[2*d+1]}, (half2v){c0[2*d], c0[2*d+1]}, s);
        s = dot2acc((half2v){ra1[2*d], ra1[2*d+1]}, (half2v){c1[2*d], c1[2*d+1]}, s);
        s = dot2acc((half2v){ra2[2*d], ra2[2*d+1]}, (half2v){c2[2*d], c2[2*d+1]}, s);
        s = dot2acc((half2v){ra3[2*d], ra3[2*d+1]}, (half2v){c3[2*d], c3[2*d+1]}, s);
    }

    s += __shfl_xor(s, 1, 64);
    s += __shfl_xor(s, 2, 64);
    s += __shfl_xor(s, 4, 64);
    s += __shfl_xor(s, 8, 64);

    if (sl == 0)
        out[e] = 1.0f / (1.0f + expf(-s));
}

// ---------------------------------------------------------------------------
// fp32 fallback path (ws too small)
// ---------------------------------------------------------------------------
#define GTM 128
#define GTN 64
#define GTK 16
#define LDA 132
#define LDB 68

__global__ __launch_bounds__(256) void gemm_zw(const float* __restrict__ A,
                                               const float* __restrict__ B,
                                               float* __restrict__ C) {
    __shared__ float As[GTK * LDA];
    __shared__ float Bs[GTK * LDB];

    const int t  = threadIdx.x;
    const int m0 = blockIdx.x * GTM;
    const int n0 = blockIdx.y * GTN;
    const int tx = t & 15;
    const int ty = t >> 4;

    float acc[8][4] = {};

    for (int k0 = 0; k0 < DIM; k0 += GTK) {
        #pragma unroll
        for (int p = 0; p < 2; ++p) {
            int f  = t + p * 256;
            int mm = f >> 2;
            int kq = f & 3;
            int m  = m0 + mm;
            float4 v = make_float4(0.f, 0.f, 0.f, 0.f);
            if (m < NNODES)
                v = *(const float4*)(A + (size_t)m * DIM + k0 + kq * 4);
            As[(kq * 4 + 0) * LDA + mm] = v.x;
            As[(kq * 4 + 1) * LDA + mm] = v.y;
            As[(kq * 4 + 2) * LDA + mm] = v.z;
            As[(kq * 4 + 3) * LDA + mm] = v.w;
        }
        {
            int kb = t >> 4, n4 = t & 15;
            *(float4*)&Bs[kb * LDB + n4 * 4] =
                *(const float4*)(B + (size_t)(k0 + kb) * DIM + n0 + n4 * 4);
        }
        __syncthreads();

        #pragma unroll
        for (int kk = 0; kk < GTK; ++kk) {
            float4 a0 = *(const float4*)&As[kk * LDA + ty * 8];
            float4 a1 = *(const float4*)&As[kk * LDA + ty * 8 + 4];
            float4 b  = *(const float4*)&Bs[kk * LDB + tx * 4];
            float av[8] = {a0.x, a0.y, a0.z, a0.w, a1.x, a1.y, a1.z, a1.w};
            float bv[4] = {b.x, b.y, b.z, b.w};
            #pragma unroll
            for (int i = 0; i < 8; ++i)
                #pragma unroll
                for (int j = 0; j < 4; ++j)
                    acc[i][j] = fmaf(av[i], bv[j], acc[i][j]);
        }
        __syncthreads();
    }

    #pragma unroll
    for (int i = 0; i < 8; ++i) {
        int m = m0 + ty * 8 + i;
        if (m < NNODES)
            *(float4*)(C + (size_t)m * DIM + n0 + tx * 4) =
                make_float4(acc[i][0], acc[i][1], acc[i][2], acc[i][3]);
    }
}

__global__ __launch_bounds__(256) void edge_score(const float* __restrict__ ZW,
                                                  const float* __restrict__ Z,
                                                  const int* __restrict__ eidx,
                                                  float* __restrict__ out) {
    const int e    = blockIdx.x * 4 + (threadIdx.x >> 6);
    const int lane = threadIdx.x & 63;

    const int r = eidx[e];
    const int c = eidx[NEDGES + e];

    const float4* pr = (const float4*)(ZW + (size_t)r * DIM);
    const float4* pc = (const float4*)(Z  + (size_t)c * DIM);

    float4 a0 = pr[lane * 2 + 0];
    float4 a1 = pr[lane * 2 + 1];
    float4 b0 = pc[lane * 2 + 0];
    float4 b1 = pc[lane * 2 + 1];

    float s = a0.x * b0.x;
    s = fmaf(a0.y, b0.y, s);
    s = fmaf(a0.z, b0.z, s);
    s = fmaf(a0.w, b0.w, s);
    s = fmaf(a1.x, b1.x, s);
    s = fmaf(a1.y, b1.y, s);
    s = fmaf(a1.z, b1.z, s);
    s = fmaf(a1.w, b1.w, s);

    #pragma unroll
    for (int off = 32; off > 0; off >>= 1)
        s += __shfl_xor(s, off, 64);

    if (lane == 0)
        out[e] = 1.0f / (1.0f + expf(-s));
}

// ---------------------------------------------------------------------------
extern "C" void kernel_launch(void* const* d_in, const int* in_sizes, int n_in,
                              void* d_out, int out_size, void* d_ws, size_t ws_size,
                              hipStream_t stream) {
    const float* Z  = (const float*)d_in[0];
    const float* W  = (const float*)d_in[1];
    const int*   EI = (const int*)d_in[2];
    float* out = (float*)d_out;

    char* p = (char*)d_ws;
    _Float16* ZWh   = (_Float16*)p;  p += (size_t)MPAD * DIM * 2;
    _Float16* Zh16  = (_Float16*)p;  p += (size_t)MPAD * DIM * 2;
    _Float16* Wh16t = (_Float16*)p;  p += (size_t)DIM * DIM * 2;
    const size_t need_full = (size_t)(p - (char*)d_ws);

    if (ws_size >= need_full) {
        prep<<<PREP_GRID, 256, 0, stream>>>(Z, W, Zh16, Wh16t);
        gemm_f16<<<GEMM_GRID, 256, 0, stream>>>(Zh16, Wh16t, ZWh);
        edge_score_u<<<NEDGES / 16, 256, 0, stream>>>(ZWh, Zh16, EI, out);
    } else {
        float* ZW = (float*)d_ws;
        dim3 g1((NNODES + GTM - 1) / GTM, DIM / GTN);
        gemm_zw<<<g1, 256, 0, stream>>>(Z, W, ZW);
        edge_score<<<NEDGES / 4, 256, 0, stream>>>(ZW, Z, EI, out);
    }
}